// Round 1
// baseline (3939.190 us; speedup 1.0000x reference)
//
#include <hip/hip_runtime.h>
#include <hip/hip_bf16.h>

// Problem constants (reference: T=2048, B=2, D_MODEL=1024, H=16, HEAD_DIM=64)
#define TT 2048
#define BB 2
#define CC 1024
#define HH 16
#define DD 64
#define MM (TT * BB)   // 4096 rows in the projection GEMMs

// ---------------------------------------------------------------------------
// Tiled NT GEMM: C[i,j] = sum_k A[i*K+k] * B[j*K+k]   (A: MxK, B: NxK row-major)
// MODE 0: plain row-major store C[M,N]
// MODE 1: QKV scatter — row i=(t*BB+b), col j=(h*DD+d) -> out[((b*HH+h)*TT+t)*DD+d]
// Tile: 64x64, BK=16, 256 threads, 4x4 accum per thread.
// ---------------------------------------------------------------------------
template <int MODE>
__global__ __launch_bounds__(256) void gemm_nt(const float* __restrict__ A,
                                               const float* __restrict__ Bm,
                                               float* __restrict__ Cc,
                                               int M, int N, int K) {
    __shared__ float As[16][65];  // [k][m], +1 pad
    __shared__ float Bs[16][65];  // [k][n], +1 pad

    const int tid = threadIdx.x;
    const int tx = tid & 15;       // 0..15 -> col group
    const int ty = tid >> 4;       // 0..15 -> row group
    const int block_m = blockIdx.x * 64;
    const int block_n = blockIdx.y * 64;

    float acc[4][4] = {};

    for (int k0 = 0; k0 < K; k0 += 16) {
        // Load 64x16 A-tile and 64x16 B-tile, 4 elements/thread each, coalesced in k.
#pragma unroll
        for (int i = 0; i < 4; i++) {
            int e = tid + i * 256;
            int r = e >> 4;        // 0..63
            int c = e & 15;        // 0..15
            As[c][r] = A[(size_t)(block_m + r) * K + k0 + c];
            Bs[c][r] = Bm[(size_t)(block_n + r) * K + k0 + c];
        }
        __syncthreads();

#pragma unroll
        for (int kk = 0; kk < 16; kk++) {
            float a[4], b[4];
#pragma unroll
            for (int i = 0; i < 4; i++) a[i] = As[kk][ty * 4 + i];
#pragma unroll
            for (int i = 0; i < 4; i++) b[i] = Bs[kk][tx * 4 + i];
#pragma unroll
            for (int i = 0; i < 4; i++)
#pragma unroll
                for (int j = 0; j < 4; j++) acc[i][j] += a[i] * b[j];
        }
        __syncthreads();
    }

#pragma unroll
    for (int i = 0; i < 4; i++) {
#pragma unroll
        for (int j = 0; j < 4; j++) {
            int row = block_m + ty * 4 + i;
            int col = block_n + tx * 4 + j;
            if (MODE == 0) {
                Cc[(size_t)row * N + col] = acc[i][j];
            } else {
                int t = row >> 1;       // BB == 2
                int b = row & 1;
                int h = col >> 6;       // DD == 64
                int d = col & 63;
                Cc[(((size_t)(b * HH + h)) * TT + t) * DD + d] = acc[i][j];
            }
        }
    }
}

// ---------------------------------------------------------------------------
// Attention: one block (256 threads) per (b,h,t) query row.
// Q,K,V in (B,H,T,D). Writes ctx in (T,B,C) layout ready for the Wo GEMM.
// Two-pass softmax with scores materialized in LDS (t+1 <= 2048 floats).
// ---------------------------------------------------------------------------
__global__ __launch_bounds__(256) void attn_kernel(const float* __restrict__ Q,
                                                   const float* __restrict__ K,
                                                   const float* __restrict__ V,
                                                   float* __restrict__ ctx) {
    const int t = blockIdx.x;     // query index
    const int bh = blockIdx.y;    // b*HH + h
    const int tid = threadIdx.x;

    __shared__ float q_s[DD];
    __shared__ float sc[TT];
    __shared__ float red[8];
    __shared__ float part[4][DD];

    const size_t base = (size_t)bh * TT * DD;

    if (tid < DD) q_s[tid] = Q[base + (size_t)t * DD + tid];
    __syncthreads();

    const float scale = 0.125f;   // 1/sqrt(64)

    // Phase 1: scores + local max. Each thread owns keys j = tid, tid+256, ...
    float lmax = -1e30f;
    for (int j = tid; j <= t; j += 256) {
        const float4* kp = (const float4*)(K + base + (size_t)j * DD);
        float s = 0.f;
#pragma unroll
        for (int u = 0; u < 16; u++) {
            float4 kv = kp[u];
            s += kv.x * q_s[u * 4 + 0] + kv.y * q_s[u * 4 + 1] +
                 kv.z * q_s[u * 4 + 2] + kv.w * q_s[u * 4 + 3];
        }
        s *= scale;
        sc[j] = s;
        lmax = fmaxf(lmax, s);
    }
    // wave (64-lane) max, then cross-wave via LDS
    for (int off = 32; off; off >>= 1) lmax = fmaxf(lmax, __shfl_xor(lmax, off));
    if ((tid & 63) == 0) red[tid >> 6] = lmax;
    __syncthreads();
    const float m = fmaxf(fmaxf(red[0], red[1]), fmaxf(red[2], red[3]));

    // Phase 2: exponentiate own scores, local sum. (Each thread re-reads only
    // its own sc[j], so no barrier needed between phase 1 and 2.)
    float lsum = 0.f;
    for (int j = tid; j <= t; j += 256) {
        float p = __expf(sc[j] - m);
        sc[j] = p;
        lsum += p;
    }
    for (int off = 32; off; off >>= 1) lsum += __shfl_xor(lsum, off);
    __syncthreads();   // everyone done reading red + writing sc
    if ((tid & 63) == 0) red[tid >> 6] = lsum;
    __syncthreads();
    const float inv_l = 1.f / (red[0] + red[1] + red[2] + red[3]);

    // Phase 3: out[d] = sum_j p_j * V[j][d]. 4 key-groups x 64 dims.
    const int d = tid & 63;
    const int g = tid >> 6;
    float acc = 0.f;
    for (int j = g; j <= t; j += 4) acc += sc[j] * V[base + (size_t)j * DD + d];
    part[g][d] = acc;
    __syncthreads();
    if (tid < DD) {
        float o = (part[0][tid] + part[1][tid] + part[2][tid] + part[3][tid]) * inv_l;
        int b = bh >> 4;
        int h = bh & 15;
        ctx[((size_t)t * BB + b) * CC + h * DD + tid] = o;
    }
}

// ---------------------------------------------------------------------------
extern "C" void kernel_launch(void* const* d_in, const int* in_sizes, int n_in,
                              void* d_out, int out_size, void* d_ws, size_t ws_size,
                              hipStream_t stream) {
    const float* x  = (const float*)d_in[0];  // (T,B,C)
    const float* Wq = (const float*)d_in[1];  // (C,C)
    const float* Wk = (const float*)d_in[2];
    const float* Wv = (const float*)d_in[3];
    const float* Wo = (const float*)d_in[4];
    float* out = (float*)d_out;               // (T,B,C) fp32

    // Workspace layout (fp32): Q | K | V | ctx, each MM*CC = 4096*1024 floats (16 MB)
    float* Qp  = (float*)d_ws;
    float* Kp  = Qp + (size_t)MM * CC;
    float* Vp  = Kp + (size_t)MM * CC;
    float* Ctx = Vp + (size_t)MM * CC;
    // requires ws_size >= 64 MB

    dim3 ggrid(MM / 64, CC / 64);  // (64,16)
    dim3 gblock(256);

    gemm_nt<1><<<ggrid, gblock, 0, stream>>>(x, Wq, Qp, MM, CC, CC);
    gemm_nt<1><<<ggrid, gblock, 0, stream>>>(x, Wk, Kp, MM, CC, CC);
    gemm_nt<1><<<ggrid, gblock, 0, stream>>>(x, Wv, Vp, MM, CC, CC);

    dim3 agrid(TT, BB * HH);       // (2048, 32)
    attn_kernel<<<agrid, dim3(256), 0, stream>>>(Qp, Kp, Vp, Ctx);

    gemm_nt<0><<<ggrid, gblock, 0, stream>>>(Ctx, Wo, out, MM, CC, CC);
}

// Round 2
// 879.364 us; speedup vs baseline: 4.4796x; 4.4796x over previous
//
#include <hip/hip_runtime.h>
#include <hip/hip_bf16.h>

// Problem constants (reference: T=2048, B=2, D_MODEL=1024, H=16, HEAD_DIM=64)
#define TT 2048
#define BB 2
#define CC 1024
#define HH 16
#define DD 64
#define MM (TT * BB)   // 4096 rows in the projection GEMMs

typedef short bf16x8 __attribute__((ext_vector_type(8)));   // 8 bf16 in 4 VGPRs
typedef float f32x4  __attribute__((ext_vector_type(4)));

// float -> bf16 (round-nearest-even), bit-level (avoids type plumbing)
__device__ inline ushort f2b(float f) {
    union { float f; unsigned u; } v; v.f = f;
    unsigned r = v.u + 0x7FFFu + ((v.u >> 16) & 1u);
    return (ushort)(r >> 16);
}

// ---------------------------------------------------------------------------
// Tiled NT GEMM: C[i,j] = sum_k A[i*K+k] * B[j*K+k]   (A: MxK, B: NxK row-major)
// MODE 0: plain row-major fp32 store C[M,N]
// MODE 1: QK scatter  — row i=(t*BB+b), col j=(h*DD+d) -> bf16 out[((b*HH+h)*TT+t)*DD+d]
// MODE 2: V scatter-T — -> bf16 out[((b*HH+h)*DD+d)*TT+t]   (B,H,D,T) for PV MFMA
// Tile: 64x64, BK=16, 256 threads, 4x4 accum per thread.
// ---------------------------------------------------------------------------
template <int MODE>
__global__ __launch_bounds__(256) void gemm_nt(const float* __restrict__ A,
                                               const float* __restrict__ Bm,
                                               void* __restrict__ Cout,
                                               int M, int N, int K) {
    __shared__ float As[16][65];  // [k][m], +1 pad
    __shared__ float Bs[16][65];  // [k][n], +1 pad

    const int tid = threadIdx.x;
    const int tx = tid & 15;
    const int ty = tid >> 4;
    const int block_m = blockIdx.x * 64;
    const int block_n = blockIdx.y * 64;

    float acc[4][4] = {};

    for (int k0 = 0; k0 < K; k0 += 16) {
#pragma unroll
        for (int i = 0; i < 4; i++) {
            int e = tid + i * 256;
            int r = e >> 4;
            int c = e & 15;
            As[c][r] = A[(size_t)(block_m + r) * K + k0 + c];
            Bs[c][r] = Bm[(size_t)(block_n + r) * K + k0 + c];
        }
        __syncthreads();

#pragma unroll
        for (int kk = 0; kk < 16; kk++) {
            float a[4], b[4];
#pragma unroll
            for (int i = 0; i < 4; i++) a[i] = As[kk][ty * 4 + i];
#pragma unroll
            for (int i = 0; i < 4; i++) b[i] = Bs[kk][tx * 4 + i];
#pragma unroll
            for (int i = 0; i < 4; i++)
#pragma unroll
                for (int j = 0; j < 4; j++) acc[i][j] += a[i] * b[j];
        }
        __syncthreads();
    }

#pragma unroll
    for (int i = 0; i < 4; i++) {
#pragma unroll
        for (int j = 0; j < 4; j++) {
            int row = block_m + ty * 4 + i;
            int col = block_n + tx * 4 + j;
            if (MODE == 0) {
                ((float*)Cout)[(size_t)row * N + col] = acc[i][j];
            } else {
                int t = row >> 1;       // BB == 2
                int b = row & 1;
                int h = col >> 6;       // DD == 64
                int d = col & 63;
                if (MODE == 1)
                    ((ushort*)Cout)[(((size_t)(b * HH + h)) * TT + t) * DD + d] = f2b(acc[i][j]);
                else
                    ((ushort*)Cout)[(((size_t)(b * HH + h)) * DD + d) * TT + t] = f2b(acc[i][j]);
            }
        }
    }
}

// ---------------------------------------------------------------------------
// Flash-style MFMA attention.
// Block = 256 threads = 4 waves; each wave owns 16 queries (block: 64).
// Q,K bf16 (B,H,T,D); V bf16 transposed (B,H,D,T). ctx fp32 (T,B,C).
// K-tiles of 64 keys staged in LDS (row stride 72 bf16 keeps b128 LDS ops
// at the 8-cycle wave floor). Online softmax in MFMA C-layout registers;
// P goes D-layout -> LDS -> A-layout for the PV MFMA (m120 pattern).
//
// mfma_f32_16x16x32_bf16 layouts (HW-verified, learn_hip m89/m91):
//   A-frag: lane holds A[m=lane&15][k=quad*8+j],  quad=lane>>4
//   B-frag: lane holds B[n=lane&15][k=quad*8+j]   (NT form: D=A.B^T)
//   C/D  :  lane holds D[row=quad*4+reg][col=lane&15]
// ---------------------------------------------------------------------------
__global__ __launch_bounds__(256) void attn_mfma(const ushort* __restrict__ Qb,
                                                 const ushort* __restrict__ Kb,
                                                 const ushort* __restrict__ Vt,
                                                 float* __restrict__ ctx) {
    __shared__ ushort Ks[64 * 72];       // [j][k]  9216 B
    __shared__ ushort Vs[64 * 72];       // [d][j]  9216 B
    __shared__ ushort Ps[4 * 16 * 72];   // per-wave P[m][j] 9216 B

    const int tid  = threadIdx.x;
    const int wave = tid >> 6;
    const int lane = tid & 63;
    const int quad = lane >> 4;
    const int l16  = lane & 15;

    const int q0 = blockIdx.x * 64;
    const int bh = blockIdx.y;
    const size_t baseQK = (size_t)bh * TT * DD;   // (B,H,T,D)
    const size_t baseVt = (size_t)bh * DD * TT;   // (B,H,D,T)

    // Q A-fragments for this wave's 16 queries, kept in registers all kernel.
    bf16x8 qa[2];
    {
        const ushort* qp = Qb + baseQK + (size_t)(q0 + wave * 16 + l16) * DD + quad * 8;
        qa[0] = *(const bf16x8*)(qp);
        qa[1] = *(const bf16x8*)(qp + 32);
    }

    f32x4 Oacc[4];
#pragma unroll
    for (int i = 0; i < 4; i++) Oacc[i] = (f32x4){0.f, 0.f, 0.f, 0.f};
    float mrun[4] = {-1e30f, -1e30f, -1e30f, -1e30f};
    float lrun[4] = {0.f, 0.f, 0.f, 0.f};

    ushort* Pw = Ps + wave * 16 * 72;

    const int ntiles = q0 / 64 + 1;   // causal: keys j <= q0+63
    for (int kt = 0; kt < ntiles; kt++) {
        const int j0 = kt * 64;

        // ---- stage K-tile and V-tile (bf16, 16B chunks, coalesced) ----
#pragma unroll
        for (int i = 0; i < 2; i++) {
            int e = tid + i * 256;       // 0..511
            int row = e >> 3, oct = e & 7;
            *(uint4*)(Ks + row * 72 + oct * 8) =
                *(const uint4*)(Kb + baseQK + (size_t)(j0 + row) * DD + oct * 8);
            *(uint4*)(Vs + row * 72 + oct * 8) =
                *(const uint4*)(Vt + baseVt + (size_t)row * TT + j0 + oct * 8);
        }
        __syncthreads();

        // ---- S = Q.K^T for 16q x 64j (8 MFMAs) ----
        f32x4 S[4];
#pragma unroll
        for (int nb = 0; nb < 4; nb++) S[nb] = (f32x4){0.f, 0.f, 0.f, 0.f};
#pragma unroll
        for (int c = 0; c < 2; c++) {
#pragma unroll
            for (int nb = 0; nb < 4; nb++) {
                bf16x8 b = *(const bf16x8*)(Ks + (nb * 16 + l16) * 72 + c * 32 + quad * 8);
                S[nb] = __builtin_amdgcn_mfma_f32_16x16x32_bf16(qa[c], b, S[nb], 0, 0, 0);
            }
        }

        // ---- online softmax (per query row m = quad*4 + r) ----
#pragma unroll
        for (int r = 0; r < 4; r++) {
            const int qg = q0 + wave * 16 + quad * 4 + r;
            float mx = -1e30f;
#pragma unroll
            for (int nb = 0; nb < 4; nb++) {
                float s = S[nb][r] * 0.125f;                 // 1/sqrt(64)
                if (j0 + nb * 16 + l16 > qg) s = -1e30f;     // causal mask
                S[nb][r] = s;
                mx = fmaxf(mx, s);
            }
            mx = fmaxf(mx, __shfl_xor(mx, 1));
            mx = fmaxf(mx, __shfl_xor(mx, 2));
            mx = fmaxf(mx, __shfl_xor(mx, 4));
            mx = fmaxf(mx, __shfl_xor(mx, 8));               // 16-lane row group

            const float mnew  = fmaxf(mrun[r], mx);
            const float alpha = __expf(mrun[r] - mnew);
            mrun[r] = mnew;

            float rsum = 0.f;
#pragma unroll
            for (int nb = 0; nb < 4; nb++) {
                float p = __expf(S[nb][r] - mnew);
                rsum += p;
                Pw[(quad * 4 + r) * 72 + nb * 16 + l16] = f2b(p);
            }
            rsum += __shfl_xor(rsum, 1);
            rsum += __shfl_xor(rsum, 2);
            rsum += __shfl_xor(rsum, 4);
            rsum += __shfl_xor(rsum, 8);
            lrun[r] = lrun[r] * alpha + rsum;
#pragma unroll
            for (int db = 0; db < 4; db++) Oacc[db][r] *= alpha;
        }

        // ---- O += P.V  (P via LDS round-trip; wave-private region) ----
#pragma unroll
        for (int c = 0; c < 2; c++) {
            bf16x8 pa = *(const bf16x8*)(Pw + l16 * 72 + c * 32 + quad * 8);
#pragma unroll
            for (int db = 0; db < 4; db++) {
                bf16x8 vb = *(const bf16x8*)(Vs + (db * 16 + l16) * 72 + c * 32 + quad * 8);
                Oacc[db] = __builtin_amdgcn_mfma_f32_16x16x32_bf16(pa, vb, Oacc[db], 0, 0, 0);
            }
        }
        __syncthreads();   // all waves done with Ks/Vs before next staging
    }

    // ---- epilogue: O /= l, write ctx (T,B,C) fp32 ----
    const int b = bh >> 4, h = bh & 15;
#pragma unroll
    for (int r = 0; r < 4; r++) {
        const int t = q0 + wave * 16 + quad * 4 + r;
        const float inv = 1.f / lrun[r];
#pragma unroll
        for (int db = 0; db < 4; db++) {
            ctx[((size_t)t * BB + b) * CC + h * DD + db * 16 + l16] = Oacc[db][r] * inv;
        }
    }
}

// ---------------------------------------------------------------------------
extern "C" void kernel_launch(void* const* d_in, const int* in_sizes, int n_in,
                              void* d_out, int out_size, void* d_ws, size_t ws_size,
                              hipStream_t stream) {
    const float* x  = (const float*)d_in[0];  // (T,B,C)
    const float* Wq = (const float*)d_in[1];  // (C,C)
    const float* Wk = (const float*)d_in[2];
    const float* Wv = (const float*)d_in[3];
    const float* Wo = (const float*)d_in[4];
    float* out = (float*)d_out;               // (T,B,C) fp32

    // Workspace: Qb | Kb (bf16, B,H,T,D) | Vt (bf16, B,H,D,T) | Ctx (fp32, T,B,C)
    ushort* Qb = (ushort*)d_ws;                       // 8 MB
    ushort* Kb = Qb + (size_t)MM * CC;                // 8 MB
    ushort* Vt = Kb + (size_t)MM * CC;                // 8 MB
    float*  Ctx = (float*)(Vt + (size_t)MM * CC);     // 16 MB  (total 40 MB)

    dim3 ggrid(MM / 64, CC / 64);  // (64,16)
    dim3 gblock(256);

    gemm_nt<1><<<ggrid, gblock, 0, stream>>>(x, Wq, Qb, MM, CC, CC);
    gemm_nt<1><<<ggrid, gblock, 0, stream>>>(x, Wk, Kb, MM, CC, CC);
    gemm_nt<2><<<ggrid, gblock, 0, stream>>>(x, Wv, Vt, MM, CC, CC);

    dim3 agrid(TT / 64, BB * HH);  // (32, 32)
    attn_mfma<<<agrid, dim3(256), 0, stream>>>(Qb, Kb, Vt, Ctx);

    gemm_nt<0><<<ggrid, gblock, 0, stream>>>(Ctx, Wo, out, MM, CC, CC);
}

// Round 3
// 260.822 us; speedup vs baseline: 15.1030x; 3.3715x over previous
//
#include <hip/hip_runtime.h>
#include <hip/hip_bf16.h>

// Problem constants (reference: T=2048, B=2, D_MODEL=1024, H=16, HEAD_DIM=64)
#define TT 2048
#define BB 2
#define CC 1024
#define HH 16
#define DD 64
#define MM (TT * BB)   // 4096 rows in the projection GEMMs

typedef short bf16x8 __attribute__((ext_vector_type(8)));   // 8 bf16 in 4 VGPRs
typedef float f32x4  __attribute__((ext_vector_type(4)));

// float -> bf16 (round-nearest-even), bit-level
__device__ inline ushort f2b(float f) {
    union { float f; unsigned u; } v; v.f = f;
    unsigned r = v.u + 0x7FFFu + ((v.u >> 16) & 1u);
    return (ushort)(r >> 16);
}

// async global->LDS, 16B per lane. LDS dst is wave-uniform base; lane i lands
// at base + i*16B (m104/m108 caveat) — all LDS tiles below are contiguous.
__device__ inline void gload_lds16(const ushort* g, ushort* l) {
    __builtin_amdgcn_global_load_lds(
        (const __attribute__((address_space(1))) void*)g,
        (__attribute__((address_space(3))) void*)l, 16, 0, 0);
}

// ---------------------------------------------------------------------------
// fp32 -> bf16 converts
// ---------------------------------------------------------------------------
__global__ __launch_bounds__(256) void conv_x(const float* __restrict__ src,
                                              ushort* __restrict__ dst) {
    int i = blockIdx.x * 256 + threadIdx.x;       // over n/4
    float4 v = ((const float4*)src)[i];
    ushort4 o = {f2b(v.x), f2b(v.y), f2b(v.z), f2b(v.w)};
    ((ushort4*)dst)[i] = o;
}

__global__ __launch_bounds__(256) void conv_w(const float* __restrict__ Wq,
                                              const float* __restrict__ Wk,
                                              const float* __restrict__ Wv,
                                              const float* __restrict__ Wo,
                                              ushort* __restrict__ dst) {
    const float* s = (blockIdx.y == 0) ? Wq : (blockIdx.y == 1) ? Wk
                   : (blockIdx.y == 2) ? Wv : Wo;
    int i = blockIdx.x * 256 + threadIdx.x;       // over CC*CC/4
    float4 v = ((const float4*)s)[i];
    ushort4 o = {f2b(v.x), f2b(v.y), f2b(v.z), f2b(v.w)};
    ((ushort4*)(dst + (size_t)blockIdx.y * CC * CC))[i] = o;
}

// ---------------------------------------------------------------------------
// bf16 MFMA NT GEMM, m97 structure: 128x128 tile, BK=32, 256 thr = 4 waves
// (2x2), each wave 64x64 via 4x4 MFMAs of 16x16x32. global_load_lds width=16.
// C[i,j] = sum_k A[i*K+k]*B[j*K+k], K == CC.
// MODE 0: fp32 row-major C[M x 1024] to Of.
// MODE 1: fused QKV (grid.y = 24): wsel = by>>3 picks B/out; epilogue scatters
//         bf16 to (B,H,T,D): row m=(t*BB+b), col=(h*DD+d).
// ---------------------------------------------------------------------------
template <int MODE>
__global__ __launch_bounds__(256) void gemm_mfma(const ushort* __restrict__ A,
                                                 const ushort* __restrict__ B0,
                                                 const ushort* __restrict__ B1,
                                                 const ushort* __restrict__ B2,
                                                 ushort* __restrict__ Oq,
                                                 ushort* __restrict__ Ok,
                                                 ushort* __restrict__ Ov,
                                                 float* __restrict__ Of) {
    __shared__ __align__(16) ushort As[128 * 32];   // [m][k] contiguous, 8 KB
    __shared__ __align__(16) ushort Bs[128 * 32];   // [n][k] contiguous, 8 KB

    const int tid = threadIdx.x;
    const int wave = tid >> 6, lane = tid & 63;
    const int quad = lane >> 4, l16 = lane & 15;
    const int wm = wave >> 1, wn = wave & 1;

    const int bm = blockIdx.x * 128;
    const ushort* Bp;
    int bn, wsel = 0;
    if (MODE == 1) {
        int by = blockIdx.y;
        wsel = by >> 3;
        Bp = (wsel == 0) ? B0 : (wsel == 1) ? B1 : B2;
        bn = (by & 7) * 128;
    } else {
        Bp = B0;
        bn = blockIdx.y * 128;
    }

    const int srow = lane >> 2;        // 0..15 staging row within 16-row chunk
    const int scol = (lane & 3) * 8;   // k-element offset (16B chunk)

    f32x4 acc[4][4];
#pragma unroll
    for (int i = 0; i < 4; i++)
#pragma unroll
        for (int j = 0; j < 4; j++) acc[i][j] = (f32x4){0.f, 0.f, 0.f, 0.f};

    for (int k0 = 0; k0 < CC; k0 += 32) {
        // stage: wave w covers rows [w*32, w*32+32) of both tiles, 2 insts each
#pragma unroll
        for (int i = 0; i < 2; i++) {
            const int rbase = wave * 32 + i * 16;
            gload_lds16(A + (size_t)(bm + rbase + srow) * CC + k0 + scol,
                        As + rbase * 32);
            gload_lds16(Bp + (size_t)(bn + rbase + srow) * CC + k0 + scol,
                        Bs + rbase * 32);
        }
        __syncthreads();   // drains vmcnt before barrier (m97 semantics)

        bf16x8 af[4], bf[4];
#pragma unroll
        for (int mi = 0; mi < 4; mi++)
            af[mi] = *(const bf16x8*)(As + (wm * 64 + mi * 16 + l16) * 32 + quad * 8);
#pragma unroll
        for (int ni = 0; ni < 4; ni++)
            bf[ni] = *(const bf16x8*)(Bs + (wn * 64 + ni * 16 + l16) * 32 + quad * 8);
#pragma unroll
        for (int mi = 0; mi < 4; mi++)
#pragma unroll
            for (int ni = 0; ni < 4; ni++)
                acc[mi][ni] = __builtin_amdgcn_mfma_f32_16x16x32_bf16(
                    af[mi], bf[ni], acc[mi][ni], 0, 0, 0);
        __syncthreads();
    }

    // epilogue: C/D layout row = quad*4+r, col = l16
#pragma unroll
    for (int mi = 0; mi < 4; mi++) {
#pragma unroll
        for (int r = 0; r < 4; r++) {
            const int m = bm + wm * 64 + mi * 16 + quad * 4 + r;
#pragma unroll
            for (int ni = 0; ni < 4; ni++) {
                const int colg = bn + wn * 64 + ni * 16 + l16;
                const float v = acc[mi][ni][r];
                if (MODE == 0) {
                    Of[(size_t)m * CC + colg] = v;
                } else {
                    const int t = m >> 1, b = m & 1;
                    const int h = colg >> 6, d = colg & 63;
                    ushort* dst = (wsel == 0) ? Oq : (wsel == 1) ? Ok : Ov;
                    dst[(((size_t)(b * HH + h)) * TT + t) * DD + d] = f2b(v);
                }
            }
        }
    }
}

// ---------------------------------------------------------------------------
// V transpose: (B,H,T,D) bf16 -> (B,H,D,T) bf16, 64x64 LDS tiles, coalesced
// global I/O on both sides.
// ---------------------------------------------------------------------------
__global__ __launch_bounds__(256) void vtrans(const ushort* __restrict__ Vb,
                                              ushort* __restrict__ Vt) {
    __shared__ __align__(16) ushort Ls[64 * 80];   // stride 80 keeps uint4 16B-aligned
    const int bh = blockIdx.y;
    const int t0 = blockIdx.x * 64;
    const int e = threadIdx.x;
    const size_t bsrc = (size_t)bh * TT * DD;
    const size_t bdst = (size_t)bh * DD * TT;

#pragma unroll
    for (int p = 0; p < 2; p++) {
        int r = p * 32 + (e >> 3);        // t-row 0..63
        int oct = e & 7;
        *(uint4*)(Ls + r * 80 + oct * 8) =
            *(const uint4*)(Vb + bsrc + (size_t)(t0 + r) * DD + oct * 8);
    }
    __syncthreads();
#pragma unroll
    for (int p = 0; p < 2; p++) {
        int d = p * 32 + (e >> 3);
        int toct = e & 7;
        ushort tmp[8];
#pragma unroll
        for (int u = 0; u < 8; u++) tmp[u] = Ls[(toct * 8 + u) * 80 + d];
        *(uint4*)(Vt + bdst + (size_t)d * TT + t0 + toct * 8) = *(uint4*)tmp;
    }
}

// ---------------------------------------------------------------------------
// Flash-style MFMA attention (unchanged from R2 except ctx is now bf16).
// ---------------------------------------------------------------------------
__global__ __launch_bounds__(256) void attn_mfma(const ushort* __restrict__ Qb,
                                                 const ushort* __restrict__ Kb,
                                                 const ushort* __restrict__ Vt,
                                                 ushort* __restrict__ ctx) {
    __shared__ ushort Ks[64 * 72];
    __shared__ ushort Vs[64 * 72];
    __shared__ ushort Ps[4 * 16 * 72];

    const int tid  = threadIdx.x;
    const int wave = tid >> 6;
    const int lane = tid & 63;
    const int quad = lane >> 4;
    const int l16  = lane & 15;

    const int q0 = blockIdx.x * 64;
    const int bh = blockIdx.y;
    const size_t baseQK = (size_t)bh * TT * DD;
    const size_t baseVt = (size_t)bh * DD * TT;

    bf16x8 qa[2];
    {
        const ushort* qp = Qb + baseQK + (size_t)(q0 + wave * 16 + l16) * DD + quad * 8;
        qa[0] = *(const bf16x8*)(qp);
        qa[1] = *(const bf16x8*)(qp + 32);
    }

    f32x4 Oacc[4];
#pragma unroll
    for (int i = 0; i < 4; i++) Oacc[i] = (f32x4){0.f, 0.f, 0.f, 0.f};
    float mrun[4] = {-1e30f, -1e30f, -1e30f, -1e30f};
    float lrun[4] = {0.f, 0.f, 0.f, 0.f};

    ushort* Pw = Ps + wave * 16 * 72;

    const int ntiles = q0 / 64 + 1;
    for (int kt = 0; kt < ntiles; kt++) {
        const int j0 = kt * 64;

#pragma unroll
        for (int i = 0; i < 2; i++) {
            int e = tid + i * 256;
            int row = e >> 3, oct = e & 7;
            *(uint4*)(Ks + row * 72 + oct * 8) =
                *(const uint4*)(Kb + baseQK + (size_t)(j0 + row) * DD + oct * 8);
            *(uint4*)(Vs + row * 72 + oct * 8) =
                *(const uint4*)(Vt + baseVt + (size_t)row * TT + j0 + oct * 8);
        }
        __syncthreads();

        f32x4 S[4];
#pragma unroll
        for (int nb = 0; nb < 4; nb++) S[nb] = (f32x4){0.f, 0.f, 0.f, 0.f};
#pragma unroll
        for (int c = 0; c < 2; c++) {
#pragma unroll
            for (int nb = 0; nb < 4; nb++) {
                bf16x8 b = *(const bf16x8*)(Ks + (nb * 16 + l16) * 72 + c * 32 + quad * 8);
                S[nb] = __builtin_amdgcn_mfma_f32_16x16x32_bf16(qa[c], b, S[nb], 0, 0, 0);
            }
        }

#pragma unroll
        for (int r = 0; r < 4; r++) {
            const int qg = q0 + wave * 16 + quad * 4 + r;
            float mx = -1e30f;
#pragma unroll
            for (int nb = 0; nb < 4; nb++) {
                float s = S[nb][r] * 0.125f;
                if (j0 + nb * 16 + l16 > qg) s = -1e30f;
                S[nb][r] = s;
                mx = fmaxf(mx, s);
            }
            mx = fmaxf(mx, __shfl_xor(mx, 1));
            mx = fmaxf(mx, __shfl_xor(mx, 2));
            mx = fmaxf(mx, __shfl_xor(mx, 4));
            mx = fmaxf(mx, __shfl_xor(mx, 8));

            const float mnew  = fmaxf(mrun[r], mx);
            const float alpha = __expf(mrun[r] - mnew);
            mrun[r] = mnew;

            float rsum = 0.f;
#pragma unroll
            for (int nb = 0; nb < 4; nb++) {
                float p = __expf(S[nb][r] - mnew);
                rsum += p;
                Pw[(quad * 4 + r) * 72 + nb * 16 + l16] = f2b(p);
            }
            rsum += __shfl_xor(rsum, 1);
            rsum += __shfl_xor(rsum, 2);
            rsum += __shfl_xor(rsum, 4);
            rsum += __shfl_xor(rsum, 8);
            lrun[r] = lrun[r] * alpha + rsum;
#pragma unroll
            for (int db = 0; db < 4; db++) Oacc[db][r] *= alpha;
        }

#pragma unroll
        for (int c = 0; c < 2; c++) {
            bf16x8 pa = *(const bf16x8*)(Pw + l16 * 72 + c * 32 + quad * 8);
#pragma unroll
            for (int db = 0; db < 4; db++) {
                bf16x8 vb = *(const bf16x8*)(Vs + (db * 16 + l16) * 72 + c * 32 + quad * 8);
                Oacc[db] = __builtin_amdgcn_mfma_f32_16x16x32_bf16(pa, vb, Oacc[db], 0, 0, 0);
            }
        }
        __syncthreads();
    }

    const int b = bh >> 4, h = bh & 15;
#pragma unroll
    for (int r = 0; r < 4; r++) {
        const int t = q0 + wave * 16 + quad * 4 + r;
        const float inv = 1.f / lrun[r];
#pragma unroll
        for (int db = 0; db < 4; db++) {
            ctx[((size_t)t * BB + b) * CC + h * DD + db * 16 + l16] =
                f2b(Oacc[db][r] * inv);
        }
    }
}

// ---------------------------------------------------------------------------
extern "C" void kernel_launch(void* const* d_in, const int* in_sizes, int n_in,
                              void* d_out, int out_size, void* d_ws, size_t ws_size,
                              hipStream_t stream) {
    const float* x  = (const float*)d_in[0];
    const float* Wq = (const float*)d_in[1];
    const float* Wk = (const float*)d_in[2];
    const float* Wv = (const float*)d_in[3];
    const float* Wo = (const float*)d_in[4];
    float* out = (float*)d_out;

    // Workspace (bf16 unless noted), each MM*CC or CC*CC elements:
    // xb 8MB | Wb 4x2MB | Qb 8 | Kb 8 | Vb 8 | Vt 8 | Ctxb 8  => 56 MB total
    ushort* xb  = (ushort*)d_ws;
    ushort* Wb  = xb + (size_t)MM * CC;
    ushort* Wqb = Wb;
    ushort* Wkb = Wb + (size_t)CC * CC;
    ushort* Wvb = Wb + 2 * (size_t)CC * CC;
    ushort* Wob = Wb + 3 * (size_t)CC * CC;
    ushort* Qb  = Wb + 4 * (size_t)CC * CC;
    ushort* Kb  = Qb + (size_t)MM * CC;
    ushort* Vb  = Kb + (size_t)MM * CC;
    ushort* Vt  = Vb + (size_t)MM * CC;
    ushort* Ctxb = Vt + (size_t)MM * CC;

    conv_x<<<dim3(MM * CC / 4 / 256), 256, 0, stream>>>(x, xb);
    conv_w<<<dim3(CC * CC / 4 / 256, 4), 256, 0, stream>>>(Wq, Wk, Wv, Wo, Wb);

    // Fused QKV: grid (32, 24); by>>3 selects {Wq->Qb, Wk->Kb, Wv->Vb}
    gemm_mfma<1><<<dim3(MM / 128, 24), 256, 0, stream>>>(
        xb, Wqb, Wkb, Wvb, Qb, Kb, Vb, nullptr);

    vtrans<<<dim3(TT / 64, BB * HH), 256, 0, stream>>>(Vb, Vt);

    attn_mfma<<<dim3(TT / 64, BB * HH), 256, 0, stream>>>(Qb, Kb, Vt, Ctxb);

    // Out-proj: ctx (bf16, row-major 4096x1024) x Wo^T -> fp32 (T,B,C)
    gemm_mfma<0><<<dim3(MM / 128, CC / 128), 256, 0, stream>>>(
        Ctxb, Wob, nullptr, nullptr, nullptr, nullptr, nullptr, out);
}

// Round 4
// 216.278 us; speedup vs baseline: 18.2136x; 1.2060x over previous
//
#include <hip/hip_runtime.h>
#include <hip/hip_bf16.h>

// Problem constants (reference: T=2048, B=2, D_MODEL=1024, H=16, HEAD_DIM=64)
#define TT 2048
#define BB 2
#define CC 1024
#define HH 16
#define DD 64
#define MM (TT * BB)   // 4096 rows in the projection GEMMs

typedef short bf16x8 __attribute__((ext_vector_type(8)));   // 8 bf16 in 4 VGPRs
typedef float f32x4  __attribute__((ext_vector_type(4)));

// float -> bf16 (round-nearest-even), bit-level
__device__ inline ushort f2b(float f) {
    union { float f; unsigned u; } v; v.f = f;
    unsigned r = v.u + 0x7FFFu + ((v.u >> 16) & 1u);
    return (ushort)(r >> 16);
}

// async global->LDS, 16B per lane. LDS dst is wave-uniform base; lane i lands
// at base + i*16B (m104/m108 caveat) — all LDS tiles below are contiguous.
__device__ inline void gload_lds16(const ushort* g, ushort* l) {
    __builtin_amdgcn_global_load_lds(
        (const __attribute__((address_space(1))) void*)g,
        (__attribute__((address_space(3))) void*)l, 16, 0, 0);
}

// ---------------------------------------------------------------------------
// fp32 -> bf16 converts
// ---------------------------------------------------------------------------
__global__ __launch_bounds__(256) void conv_x(const float* __restrict__ src,
                                              ushort* __restrict__ dst) {
    int i = blockIdx.x * 256 + threadIdx.x;       // over n/4
    float4 v = ((const float4*)src)[i];
    ushort4 o = {f2b(v.x), f2b(v.y), f2b(v.z), f2b(v.w)};
    ((ushort4*)dst)[i] = o;
}

__global__ __launch_bounds__(256) void conv_w(const float* __restrict__ Wq,
                                              const float* __restrict__ Wk,
                                              const float* __restrict__ Wv,
                                              const float* __restrict__ Wo,
                                              ushort* __restrict__ dst) {
    const float* s = (blockIdx.y == 0) ? Wq : (blockIdx.y == 1) ? Wk
                   : (blockIdx.y == 2) ? Wv : Wo;
    int i = blockIdx.x * 256 + threadIdx.x;       // over CC*CC/4
    float4 v = ((const float4*)s)[i];
    ushort4 o = {f2b(v.x), f2b(v.y), f2b(v.z), f2b(v.w)};
    ((ushort4*)(dst + (size_t)blockIdx.y * CC * CC))[i] = o;
}

// ---------------------------------------------------------------------------
// bf16 MFMA NT GEMM, m97 structure: 128x128 tile, BK=32, 256 thr = 4 waves
// (2x2), each wave 64x64 via 4x4 MFMAs of 16x16x32. global_load_lds width=16.
// C[i,j] = sum_k A[i*K+k]*B[j*K+k], K == CC.
// MODE 0: fp32 row-major C[M x 1024] to Of.
// MODE 1: fused QKV (grid.y = 24): wsel = by>>3 picks B/out; epilogue scatters
//         bf16 to (B,H,T,D). Q additionally scaled by 1/sqrt(64) (exact in
//         bf16 — power of two), so attention skips the per-score scale.
// ---------------------------------------------------------------------------
template <int MODE>
__global__ __launch_bounds__(256) void gemm_mfma(const ushort* __restrict__ A,
                                                 const ushort* __restrict__ B0,
                                                 const ushort* __restrict__ B1,
                                                 const ushort* __restrict__ B2,
                                                 ushort* __restrict__ Oq,
                                                 ushort* __restrict__ Ok,
                                                 ushort* __restrict__ Ov,
                                                 float* __restrict__ Of) {
    __shared__ __align__(16) ushort As[128 * 32];   // [m][k] contiguous, 8 KB
    __shared__ __align__(16) ushort Bs[128 * 32];   // [n][k] contiguous, 8 KB

    const int tid = threadIdx.x;
    const int wave = tid >> 6, lane = tid & 63;
    const int quad = lane >> 4, l16 = lane & 15;
    const int wm = wave >> 1, wn = wave & 1;

    const int bm = blockIdx.x * 128;
    const ushort* Bp;
    int bn, wsel = 0;
    if (MODE == 1) {
        int by = blockIdx.y;
        wsel = by >> 3;
        Bp = (wsel == 0) ? B0 : (wsel == 1) ? B1 : B2;
        bn = (by & 7) * 128;
    } else {
        Bp = B0;
        bn = blockIdx.y * 128;
    }

    const int srow = lane >> 2;        // 0..15 staging row within 16-row chunk
    const int scol = (lane & 3) * 8;   // k-element offset (16B chunk)

    f32x4 acc[4][4];
#pragma unroll
    for (int i = 0; i < 4; i++)
#pragma unroll
        for (int j = 0; j < 4; j++) acc[i][j] = (f32x4){0.f, 0.f, 0.f, 0.f};

    for (int k0 = 0; k0 < CC; k0 += 32) {
#pragma unroll
        for (int i = 0; i < 2; i++) {
            const int rbase = wave * 32 + i * 16;
            gload_lds16(A + (size_t)(bm + rbase + srow) * CC + k0 + scol,
                        As + rbase * 32);
            gload_lds16(Bp + (size_t)(bn + rbase + srow) * CC + k0 + scol,
                        Bs + rbase * 32);
        }
        __syncthreads();

        bf16x8 af[4], bf[4];
#pragma unroll
        for (int mi = 0; mi < 4; mi++)
            af[mi] = *(const bf16x8*)(As + (wm * 64 + mi * 16 + l16) * 32 + quad * 8);
#pragma unroll
        for (int ni = 0; ni < 4; ni++)
            bf[ni] = *(const bf16x8*)(Bs + (wn * 64 + ni * 16 + l16) * 32 + quad * 8);
#pragma unroll
        for (int mi = 0; mi < 4; mi++)
#pragma unroll
            for (int ni = 0; ni < 4; ni++)
                acc[mi][ni] = __builtin_amdgcn_mfma_f32_16x16x32_bf16(
                    af[mi], bf[ni], acc[mi][ni], 0, 0, 0);
        __syncthreads();
    }

    // epilogue: C/D layout row = quad*4+r, col = l16
    const float oscale = (MODE == 1 && /* Q? */ true) ? 1.f : 1.f; // see below
#pragma unroll
    for (int mi = 0; mi < 4; mi++) {
#pragma unroll
        for (int r = 0; r < 4; r++) {
            const int m = bm + wm * 64 + mi * 16 + quad * 4 + r;
#pragma unroll
            for (int ni = 0; ni < 4; ni++) {
                const int colg = bn + wn * 64 + ni * 16 + l16;
                float v = acc[mi][ni][r];
                if (MODE == 0) {
                    Of[(size_t)m * CC + colg] = v;
                } else {
                    if (wsel == 0) v *= 0.125f;   // fold 1/sqrt(DD) into Q
                    const int t = m >> 1, b = m & 1;
                    const int h = colg >> 6, d = colg & 63;
                    ushort* dst = (wsel == 0) ? Oq : (wsel == 1) ? Ok : Ov;
                    dst[(((size_t)(b * HH + h)) * TT + t) * DD + d] = f2b(v);
                }
            }
        }
    }
    (void)oscale;
}

// ---------------------------------------------------------------------------
// V transpose: (B,H,T,D) bf16 -> (B,H,D,T) bf16, 64x64 LDS tiles.
// ---------------------------------------------------------------------------
__global__ __launch_bounds__(256) void vtrans(const ushort* __restrict__ Vb,
                                              ushort* __restrict__ Vt) {
    __shared__ __align__(16) ushort Ls[64 * 80];
    const int bh = blockIdx.y;
    const int t0 = blockIdx.x * 64;
    const int e = threadIdx.x;
    const size_t bsrc = (size_t)bh * TT * DD;
    const size_t bdst = (size_t)bh * DD * TT;

#pragma unroll
    for (int p = 0; p < 2; p++) {
        int r = p * 32 + (e >> 3);
        int oct = e & 7;
        *(uint4*)(Ls + r * 80 + oct * 8) =
            *(const uint4*)(Vb + bsrc + (size_t)(t0 + r) * DD + oct * 8);
    }
    __syncthreads();
#pragma unroll
    for (int p = 0; p < 2; p++) {
        int d = p * 32 + (e >> 3);
        int toct = e & 7;
        ushort tmp[8];
#pragma unroll
        for (int u = 0; u < 8; u++) tmp[u] = Ls[(toct * 8 + u) * 80 + d];
        *(uint4*)(Vt + bdst + (size_t)d * TT + t0 + toct * 8) = *(uint4*)tmp;
    }
}

// ---------------------------------------------------------------------------
// Flash attention step for one 64-key tile against one wave's 16 queries.
// Q pre-scaled by 1/sqrt(64). DIAG: apply causal mask (diagonal tile only).
// ---------------------------------------------------------------------------
template <bool DIAG>
__device__ __forceinline__ void attn_step(const bf16x8* qa, f32x4* Oacc,
                                          float* mrun, float* lrun,
                                          const ushort* Ks, const ushort* Vs,
                                          ushort* Pw, int j0, int qbase,
                                          int quad, int l16) {
    f32x4 S[4];
#pragma unroll
    for (int nb = 0; nb < 4; nb++) S[nb] = (f32x4){0.f, 0.f, 0.f, 0.f};
#pragma unroll
    for (int c = 0; c < 2; c++) {
#pragma unroll
        for (int nb = 0; nb < 4; nb++) {
            bf16x8 b = *(const bf16x8*)(Ks + (nb * 16 + l16) * 72 + c * 32 + quad * 8);
            S[nb] = __builtin_amdgcn_mfma_f32_16x16x32_bf16(qa[c], b, S[nb], 0, 0, 0);
        }
    }

#pragma unroll
    for (int r = 0; r < 4; r++) {
        const int qg = qbase + quad * 4 + r;
        float mx = -1e30f;
#pragma unroll
        for (int nb = 0; nb < 4; nb++) {
            float s = S[nb][r];
            if (DIAG) {
                if (j0 + nb * 16 + l16 > qg) s = -1e30f;
            }
            S[nb][r] = s;
            mx = fmaxf(mx, s);
        }
        mx = fmaxf(mx, __shfl_xor(mx, 1));
        mx = fmaxf(mx, __shfl_xor(mx, 2));
        mx = fmaxf(mx, __shfl_xor(mx, 4));
        mx = fmaxf(mx, __shfl_xor(mx, 8));   // 16-lane row group

        const float mnew  = fmaxf(mrun[r], mx);
        const float alpha = __expf(mrun[r] - mnew);
        mrun[r] = mnew;

        float rsum = 0.f;
#pragma unroll
        for (int nb = 0; nb < 4; nb++) {
            float pv = __expf(S[nb][r] - mnew);
            rsum += pv;
            Pw[(quad * 4 + r) * 72 + nb * 16 + l16] = f2b(pv);
        }
        rsum += __shfl_xor(rsum, 1);
        rsum += __shfl_xor(rsum, 2);
        rsum += __shfl_xor(rsum, 4);
        rsum += __shfl_xor(rsum, 8);
        lrun[r] = lrun[r] * alpha + rsum;
#pragma unroll
        for (int db = 0; db < 4; db++) Oacc[db][r] *= alpha;
    }

#pragma unroll
    for (int c = 0; c < 2; c++) {
        bf16x8 pa = *(const bf16x8*)(Pw + l16 * 72 + c * 32 + quad * 8);
#pragma unroll
        for (int db = 0; db < 4; db++) {
            bf16x8 vb = *(const bf16x8*)(Vs + (db * 16 + l16) * 72 + c * 32 + quad * 8);
            Oacc[db] = __builtin_amdgcn_mfma_f32_16x16x32_bf16(pa, vb, Oacc[db], 0, 0, 0);
        }
    }
}

// ---------------------------------------------------------------------------
// Paired-tile flash MFMA attention: block p handles q-tiles p and 31-p
// (exactly 33 tile-visits per block — uniform load across all 512 blocks).
// Each K/V tile is staged ONCE and consumed by both q-sets.
// ---------------------------------------------------------------------------
__global__ __launch_bounds__(256) void attn_mfma(const ushort* __restrict__ Qb,
                                                 const ushort* __restrict__ Kb,
                                                 const ushort* __restrict__ Vt,
                                                 ushort* __restrict__ ctx) {
    __shared__ ushort Ks[64 * 72];       // [j][k]  9216 B
    __shared__ ushort Vs[64 * 72];       // [d][j]  9216 B
    __shared__ ushort Ps[4 * 16 * 72];   // per-wave P[m][j] 9216 B

    const int tid  = threadIdx.x;
    const int wave = tid >> 6;
    const int lane = tid & 63;
    const int quad = lane >> 4;
    const int l16  = lane & 15;

    const int p  = blockIdx.x;                    // 0..15
    const int bh = blockIdx.y;
    const int qtA = p, qtB = (TT / 64 - 1) - p;   // 31-p >= 16 > p
    const int q0A = qtA * 64 + wave * 16;         // this wave's query base
    const int q0B = qtB * 64 + wave * 16;

    const size_t baseQK = (size_t)bh * TT * DD;
    const size_t baseVt = (size_t)bh * DD * TT;

    bf16x8 qaA[2], qaB[2];
    {
        const ushort* qp = Qb + baseQK + (size_t)(q0A + l16) * DD + quad * 8;
        qaA[0] = *(const bf16x8*)(qp);
        qaA[1] = *(const bf16x8*)(qp + 32);
        const ushort* qp2 = Qb + baseQK + (size_t)(q0B + l16) * DD + quad * 8;
        qaB[0] = *(const bf16x8*)(qp2);
        qaB[1] = *(const bf16x8*)(qp2 + 32);
    }

    f32x4 OA[4], OB[4];
#pragma unroll
    for (int i = 0; i < 4; i++) {
        OA[i] = (f32x4){0.f, 0.f, 0.f, 0.f};
        OB[i] = (f32x4){0.f, 0.f, 0.f, 0.f};
    }
    float mA[4] = {-1e30f, -1e30f, -1e30f, -1e30f};
    float mB[4] = {-1e30f, -1e30f, -1e30f, -1e30f};
    float lA[4] = {0.f, 0.f, 0.f, 0.f};
    float lB[4] = {0.f, 0.f, 0.f, 0.f};

    ushort* Pw = Ps + wave * 16 * 72;

    for (int kt = 0; kt <= qtB; kt++) {
        const int j0 = kt * 64;

        // ---- stage K-tile and V-tile (shared by both q-sets) ----
#pragma unroll
        for (int i = 0; i < 2; i++) {
            int e = tid + i * 256;
            int row = e >> 3, oct = e & 7;
            *(uint4*)(Ks + row * 72 + oct * 8) =
                *(const uint4*)(Kb + baseQK + (size_t)(j0 + row) * DD + oct * 8);
            *(uint4*)(Vs + row * 72 + oct * 8) =
                *(const uint4*)(Vt + baseVt + (size_t)row * TT + j0 + oct * 8);
        }
        __syncthreads();

        if (kt == qtB)
            attn_step<true >(qaB, OB, mB, lB, Ks, Vs, Pw, j0, q0B, quad, l16);
        else
            attn_step<false>(qaB, OB, mB, lB, Ks, Vs, Pw, j0, q0B, quad, l16);

        if (kt <= qtA) {
            if (kt == qtA)
                attn_step<true >(qaA, OA, mA, lA, Ks, Vs, Pw, j0, q0A, quad, l16);
            else
                attn_step<false>(qaA, OA, mA, lA, Ks, Vs, Pw, j0, q0A, quad, l16);
        }
        __syncthreads();
    }

    // ---- epilogue: O /= l, write ctx (T,B,C) bf16 for both q-sets ----
    const int b = bh >> 4, h = bh & 15;
#pragma unroll
    for (int r = 0; r < 4; r++) {
        const int tA = q0A + quad * 4 + r;
        const int tB = q0B + quad * 4 + r;
        const float invA = 1.f / lA[r];
        const float invB = 1.f / lB[r];
#pragma unroll
        for (int db = 0; db < 4; db++) {
            ctx[((size_t)tA * BB + b) * CC + h * DD + db * 16 + l16] =
                f2b(OA[db][r] * invA);
            ctx[((size_t)tB * BB + b) * CC + h * DD + db * 16 + l16] =
                f2b(OB[db][r] * invB);
        }
    }
}

// ---------------------------------------------------------------------------
extern "C" void kernel_launch(void* const* d_in, const int* in_sizes, int n_in,
                              void* d_out, int out_size, void* d_ws, size_t ws_size,
                              hipStream_t stream) {
    const float* x  = (const float*)d_in[0];
    const float* Wq = (const float*)d_in[1];
    const float* Wk = (const float*)d_in[2];
    const float* Wv = (const float*)d_in[3];
    const float* Wo = (const float*)d_in[4];
    float* out = (float*)d_out;

    // Workspace (bf16): xb 8MB | Wb 4x2MB | Qb 8 | Kb 8 | Vb 8 | Vt 8 | Ctxb 8
    ushort* xb  = (ushort*)d_ws;
    ushort* Wb  = xb + (size_t)MM * CC;
    ushort* Wqb = Wb;
    ushort* Wkb = Wb + (size_t)CC * CC;
    ushort* Wvb = Wb + 2 * (size_t)CC * CC;
    ushort* Wob = Wb + 3 * (size_t)CC * CC;
    ushort* Qb  = Wb + 4 * (size_t)CC * CC;
    ushort* Kb  = Qb + (size_t)MM * CC;
    ushort* Vb  = Kb + (size_t)MM * CC;
    ushort* Vt  = Vb + (size_t)MM * CC;
    ushort* Ctxb = Vt + (size_t)MM * CC;

    conv_x<<<dim3(MM * CC / 4 / 256), 256, 0, stream>>>(x, xb);
    conv_w<<<dim3(CC * CC / 4 / 256, 4), 256, 0, stream>>>(Wq, Wk, Wv, Wo, Wb);

    gemm_mfma<1><<<dim3(MM / 128, 24), 256, 0, stream>>>(
        xb, Wqb, Wkb, Wvb, Qb, Kb, Vb, nullptr);

    vtrans<<<dim3(TT / 64, BB * HH), 256, 0, stream>>>(Vb, Vt);

    attn_mfma<<<dim3(TT / 128, BB * HH), 256, 0, stream>>>(Qb, Kb, Vt, Ctxb);

    gemm_mfma<0><<<dim3(MM / 128, CC / 128), 256, 0, stream>>>(
        Ctxb, Wob, nullptr, nullptr, nullptr, nullptr, nullptr, out);
}

// Round 5
// 187.100 us; speedup vs baseline: 21.0539x; 1.1559x over previous
//
#include <hip/hip_runtime.h>
#include <hip/hip_bf16.h>

// Problem constants (reference: T=2048, B=2, D_MODEL=1024, H=16, HEAD_DIM=64)
#define TT 2048
#define BB 2
#define CC 1024
#define HH 16
#define DD 64
#define MM (TT * BB)   // 4096 rows in the projection GEMMs

typedef short bf16x8 __attribute__((ext_vector_type(8)));   // 8 bf16 in 4 VGPRs
typedef float f32x4  __attribute__((ext_vector_type(4)));

// float -> bf16 (round-nearest-even), bit-level
__device__ inline ushort f2b(float f) {
    union { float f; unsigned u; } v; v.f = f;
    unsigned r = v.u + 0x7FFFu + ((v.u >> 16) & 1u);
    return (ushort)(r >> 16);
}

// pack 2 floats -> 2 bf16 in one dword (v_cvt_pk_bf16_f32 on gfx950)
__device__ inline unsigned pack_bf16(float a, float b) {
    __hip_bfloat162 h = __float22bfloat162_rn(make_float2(a, b));
    union { __hip_bfloat162 h; unsigned u; } c; c.h = h;
    return c.u;
}

// async global->LDS, 16B per lane (GEMM staging only)
__device__ inline void gload_lds16(const ushort* g, ushort* l) {
    __builtin_amdgcn_global_load_lds(
        (const __attribute__((address_space(1))) void*)g,
        (__attribute__((address_space(3))) void*)l, 16, 0, 0);
}

// ---------------------------------------------------------------------------
// fp32 -> bf16 converts
// ---------------------------------------------------------------------------
__global__ __launch_bounds__(256) void conv_x(const float* __restrict__ src,
                                              ushort* __restrict__ dst) {
    int i = blockIdx.x * 256 + threadIdx.x;
    float4 v = ((const float4*)src)[i];
    ushort4 o = {f2b(v.x), f2b(v.y), f2b(v.z), f2b(v.w)};
    ((ushort4*)dst)[i] = o;
}

__global__ __launch_bounds__(256) void conv_w(const float* __restrict__ Wq,
                                              const float* __restrict__ Wk,
                                              const float* __restrict__ Wv,
                                              const float* __restrict__ Wo,
                                              ushort* __restrict__ dst) {
    const float* s = (blockIdx.y == 0) ? Wq : (blockIdx.y == 1) ? Wk
                   : (blockIdx.y == 2) ? Wv : Wo;
    int i = blockIdx.x * 256 + threadIdx.x;
    float4 v = ((const float4*)s)[i];
    ushort4 o = {f2b(v.x), f2b(v.y), f2b(v.z), f2b(v.w)};
    ((ushort4*)(dst + (size_t)blockIdx.y * CC * CC))[i] = o;
}

// ---------------------------------------------------------------------------
// bf16 MFMA NT GEMM (m97 structure), 128x128 tile, BK=32, 4 waves (2x2).
// MODE 0: fp32 row-major out. MODE 1: fused QKV scatter to (B,H,T,D) bf16;
// Q scaled by 1/sqrt(64)*log2(e) so attention can use exp2 directly.
// ---------------------------------------------------------------------------
template <int MODE>
__global__ __launch_bounds__(256) void gemm_mfma(const ushort* __restrict__ A,
                                                 const ushort* __restrict__ B0,
                                                 const ushort* __restrict__ B1,
                                                 const ushort* __restrict__ B2,
                                                 ushort* __restrict__ Oq,
                                                 ushort* __restrict__ Ok,
                                                 ushort* __restrict__ Ov,
                                                 float* __restrict__ Of) {
    __shared__ __align__(16) ushort As[128 * 32];
    __shared__ __align__(16) ushort Bs[128 * 32];

    const int tid = threadIdx.x;
    const int wave = tid >> 6, lane = tid & 63;
    const int quad = lane >> 4, l16 = lane & 15;
    const int wm = wave >> 1, wn = wave & 1;

    const int bm = blockIdx.x * 128;
    const ushort* Bp;
    int bn, wsel = 0;
    if (MODE == 1) {
        int by = blockIdx.y;
        wsel = by >> 3;
        Bp = (wsel == 0) ? B0 : (wsel == 1) ? B1 : B2;
        bn = (by & 7) * 128;
    } else {
        Bp = B0;
        bn = blockIdx.y * 128;
    }

    const int srow = lane >> 2;
    const int scol = (lane & 3) * 8;

    f32x4 acc[4][4];
#pragma unroll
    for (int i = 0; i < 4; i++)
#pragma unroll
        for (int j = 0; j < 4; j++) acc[i][j] = (f32x4){0.f, 0.f, 0.f, 0.f};

    for (int k0 = 0; k0 < CC; k0 += 32) {
#pragma unroll
        for (int i = 0; i < 2; i++) {
            const int rbase = wave * 32 + i * 16;
            gload_lds16(A + (size_t)(bm + rbase + srow) * CC + k0 + scol,
                        As + rbase * 32);
            gload_lds16(Bp + (size_t)(bn + rbase + srow) * CC + k0 + scol,
                        Bs + rbase * 32);
        }
        __syncthreads();

        bf16x8 af[4], bf[4];
#pragma unroll
        for (int mi = 0; mi < 4; mi++)
            af[mi] = *(const bf16x8*)(As + (wm * 64 + mi * 16 + l16) * 32 + quad * 8);
#pragma unroll
        for (int ni = 0; ni < 4; ni++)
            bf[ni] = *(const bf16x8*)(Bs + (wn * 64 + ni * 16 + l16) * 32 + quad * 8);
#pragma unroll
        for (int mi = 0; mi < 4; mi++)
#pragma unroll
            for (int ni = 0; ni < 4; ni++)
                acc[mi][ni] = __builtin_amdgcn_mfma_f32_16x16x32_bf16(
                    af[mi], bf[ni], acc[mi][ni], 0, 0, 0);
        __syncthreads();
    }

#pragma unroll
    for (int mi = 0; mi < 4; mi++) {
#pragma unroll
        for (int r = 0; r < 4; r++) {
            const int m = bm + wm * 64 + mi * 16 + quad * 4 + r;
#pragma unroll
            for (int ni = 0; ni < 4; ni++) {
                const int colg = bn + wn * 64 + ni * 16 + l16;
                float v = acc[mi][ni][r];
                if (MODE == 0) {
                    Of[(size_t)m * CC + colg] = v;
                } else {
                    // Q: fold 1/sqrt(64) * log2(e) so attn uses exp2(s) raw
                    if (wsel == 0) v *= 0.18033688f;
                    const int t = m >> 1, b = m & 1;
                    const int h = colg >> 6, d = colg & 63;
                    ushort* dst = (wsel == 0) ? Oq : (wsel == 1) ? Ok : Ov;
                    dst[(((size_t)(b * HH + h)) * TT + t) * DD + d] = f2b(v);
                }
            }
        }
    }
}

// ---------------------------------------------------------------------------
// V transpose with baked column permutation: within each 64-key tile the
// output column j' holds key j = (j'&3)*16 + (j'>>2). The attention kernel's
// packed P-writes use j' = (j&15)*4 + (j>>4); PV is invariant to a shared
// permutation of the key axis.
// ---------------------------------------------------------------------------
__global__ __launch_bounds__(256) void vtrans(const ushort* __restrict__ Vb,
                                              ushort* __restrict__ Vt) {
    __shared__ __align__(16) ushort Ls[64 * 80];
    const int bh = blockIdx.y;
    const int t0 = blockIdx.x * 64;
    const int e = threadIdx.x;
    const size_t bsrc = (size_t)bh * TT * DD;
    const size_t bdst = (size_t)bh * DD * TT;

#pragma unroll
    for (int p = 0; p < 2; p++) {
        int r = p * 32 + (e >> 3);
        int oct = e & 7;
        *(uint4*)(Ls + r * 80 + oct * 8) =
            *(const uint4*)(Vb + bsrc + (size_t)(t0 + r) * DD + oct * 8);
    }
    __syncthreads();
#pragma unroll
    for (int p = 0; p < 2; p++) {
        int d = p * 32 + (e >> 3);
        int toct = e & 7;
        ushort tmp[8];
#pragma unroll
        for (int u = 0; u < 8; u++) {
            int jp = toct * 8 + u;                     // output column j'
            int js = (jp & 3) * 16 + (jp >> 2);        // source key index
            tmp[u] = Ls[js * 80 + d];
        }
        *(uint4*)(Vt + bdst + (size_t)d * TT + t0 + toct * 8) = *(uint4*)tmp;
    }
}

// ---------------------------------------------------------------------------
// One 64-key tile vs one wave's 16 queries. Max-free softmax:
// p = exp2(min(s,60)) (Q pre-scaled by 0.125*log2e). l accumulated per-lane.
// kf/vf: shared K/V B-fragments (identical for both q-sets). Pw: wave-private.
// ---------------------------------------------------------------------------
template <bool DIAG>
__device__ __forceinline__ void attn_step(const bf16x8* qa, f32x4* Oacc,
                                          float* lrun,
                                          const bf16x8* kf, const bf16x8* vf,
                                          ushort* Pw, int j0, int qbase,
                                          int quad, int l16) {
    f32x4 S[4];
#pragma unroll
    for (int nb = 0; nb < 4; nb++) S[nb] = (f32x4){0.f, 0.f, 0.f, 0.f};
#pragma unroll
    for (int c = 0; c < 2; c++)
#pragma unroll
        for (int nb = 0; nb < 4; nb++)
            S[nb] = __builtin_amdgcn_mfma_f32_16x16x32_bf16(qa[c], kf[c * 4 + nb],
                                                            S[nb], 0, 0, 0);

#pragma unroll
    for (int r = 0; r < 4; r++) {
        const int qg = qbase + quad * 4 + r;
        float p[4];
#pragma unroll
        for (int nb = 0; nb < 4; nb++) {
            float s = S[nb][r];
            if (DIAG) {
                if (j0 + nb * 16 + l16 > qg) s = -1e30f;
            }
            p[nb] = __builtin_amdgcn_exp2f(fminf(s, 60.f));  // masked -> 0
        }
        lrun[r] += (p[0] + p[1]) + (p[2] + p[3]);
        // packed write: P row m=quad*4+r, columns j' = l16*4 + {0,1,2,3}
        uint2 w;
        w.x = pack_bf16(p[0], p[1]);
        w.y = pack_bf16(p[2], p[3]);
        *(uint2*)(Pw + (quad * 4 + r) * 72 + l16 * 4) = w;
    }

#pragma unroll
    for (int c = 0; c < 2; c++) {
        bf16x8 pa = *(const bf16x8*)(Pw + l16 * 72 + c * 32 + quad * 8);
#pragma unroll
        for (int db = 0; db < 4; db++)
            Oacc[db] = __builtin_amdgcn_mfma_f32_16x16x32_bf16(pa, vf[c * 4 + db],
                                                               Oacc[db], 0, 0, 0);
    }
}

// ---------------------------------------------------------------------------
// Paired-tile flash MFMA attention: block p handles q-tiles p and 31-p
// (uniform 33 tile-visits). K/V staged once per tile for both q-sets, with
// register prefetch of tile kt+1 overlapping compute on tile kt.
// ---------------------------------------------------------------------------
__global__ __launch_bounds__(256, 2) void attn_mfma(const ushort* __restrict__ Qb,
                                                    const ushort* __restrict__ Kb,
                                                    const ushort* __restrict__ Vt,
                                                    ushort* __restrict__ ctx) {
    __shared__ __align__(16) ushort Ks[64 * 72];       // [j][k]
    __shared__ __align__(16) ushort Vs[64 * 72];       // [d][j']
    __shared__ __align__(16) ushort Ps[4 * 16 * 72];   // per-wave P[m][j']

    const int tid  = threadIdx.x;
    const int wave = tid >> 6;
    const int lane = tid & 63;
    const int quad = lane >> 4;
    const int l16  = lane & 15;

    const int p  = blockIdx.x;                    // 0..15
    const int bh = blockIdx.y;
    const int qtA = p, qtB = (TT / 64 - 1) - p;
    const int q0A = qtA * 64 + wave * 16;
    const int q0B = qtB * 64 + wave * 16;

    const size_t baseQK = (size_t)bh * TT * DD;
    const size_t baseVt = (size_t)bh * DD * TT;

    bf16x8 qaA[2], qaB[2];
    {
        const ushort* qp = Qb + baseQK + (size_t)(q0A + l16) * DD + quad * 8;
        qaA[0] = *(const bf16x8*)(qp);
        qaA[1] = *(const bf16x8*)(qp + 32);
        const ushort* qp2 = Qb + baseQK + (size_t)(q0B + l16) * DD + quad * 8;
        qaB[0] = *(const bf16x8*)(qp2);
        qaB[1] = *(const bf16x8*)(qp2 + 32);
    }

    f32x4 OA[4], OB[4];
#pragma unroll
    for (int i = 0; i < 4; i++) {
        OA[i] = (f32x4){0.f, 0.f, 0.f, 0.f};
        OB[i] = (f32x4){0.f, 0.f, 0.f, 0.f};
    }
    float lA[4] = {0.f, 0.f, 0.f, 0.f};
    float lB[4] = {0.f, 0.f, 0.f, 0.f};

    ushort* Pw = Ps + wave * 16 * 72;

    // staging geometry: each thread owns rows (tid>>3) and (tid>>3)+32, 16B col chunk
    const int row0 = tid >> 3;
    const int oct  = tid & 7;

    uint4 kr0, kr1, vr0, vr1;
    // prefetch tile 0
    kr0 = *(const uint4*)(Kb + baseQK + (size_t)row0 * DD + oct * 8);
    kr1 = *(const uint4*)(Kb + baseQK + (size_t)(row0 + 32) * DD + oct * 8);
    vr0 = *(const uint4*)(Vt + baseVt + (size_t)row0 * TT + oct * 8);
    vr1 = *(const uint4*)(Vt + baseVt + (size_t)(row0 + 32) * TT + oct * 8);

    for (int kt = 0; kt <= qtB; kt++) {
        const int j0 = kt * 64;

        // commit prefetched tile to LDS
        *(uint4*)(Ks + row0 * 72 + oct * 8) = kr0;
        *(uint4*)(Ks + (row0 + 32) * 72 + oct * 8) = kr1;
        *(uint4*)(Vs + row0 * 72 + oct * 8) = vr0;
        *(uint4*)(Vs + (row0 + 32) * 72 + oct * 8) = vr1;
        __syncthreads();

        // issue prefetch for tile kt+1 (latency overlaps compute below)
        if (kt < qtB) {
            const int jn = j0 + 64;
            kr0 = *(const uint4*)(Kb + baseQK + (size_t)(jn + row0) * DD + oct * 8);
            kr1 = *(const uint4*)(Kb + baseQK + (size_t)(jn + row0 + 32) * DD + oct * 8);
            vr0 = *(const uint4*)(Vt + baseVt + (size_t)row0 * TT + jn + oct * 8);
            vr1 = *(const uint4*)(Vt + baseVt + (size_t)(row0 + 32) * TT + jn + oct * 8);
        }

        // shared K/V fragments — identical for both q-sets, loaded once
        bf16x8 kf[8], vf[8];
#pragma unroll
        for (int c = 0; c < 2; c++)
#pragma unroll
            for (int nb = 0; nb < 4; nb++) {
                kf[c * 4 + nb] = *(const bf16x8*)(Ks + (nb * 16 + l16) * 72 + c * 32 + quad * 8);
                vf[c * 4 + nb] = *(const bf16x8*)(Vs + (nb * 16 + l16) * 72 + c * 32 + quad * 8);
            }

        if (kt == qtB)
            attn_step<true >(qaB, OB, lB, kf, vf, Pw, j0, q0B, quad, l16);
        else
            attn_step<false>(qaB, OB, lB, kf, vf, Pw, j0, q0B, quad, l16);

        if (kt <= qtA) {
            if (kt == qtA)
                attn_step<true >(qaA, OA, lA, kf, vf, Pw, j0, q0A, quad, l16);
            else
                attn_step<false>(qaA, OA, lA, kf, vf, Pw, j0, q0A, quad, l16);
        }
        __syncthreads();
    }

    // epilogue: row-reduce l across the 16-lane groups, normalize, store bf16
    const int b = bh >> 4, h = bh & 15;
#pragma unroll
    for (int r = 0; r < 4; r++) {
        float la = lA[r], lb = lB[r];
        la += __shfl_xor(la, 1); la += __shfl_xor(la, 2);
        la += __shfl_xor(la, 4); la += __shfl_xor(la, 8);
        lb += __shfl_xor(lb, 1); lb += __shfl_xor(lb, 2);
        lb += __shfl_xor(lb, 4); lb += __shfl_xor(lb, 8);
        const float invA = 1.f / la;
        const float invB = 1.f / lb;
        const int tA = q0A + quad * 4 + r;
        const int tB = q0B + quad * 4 + r;
#pragma unroll
        for (int db = 0; db < 4; db++) {
            ctx[((size_t)tA * BB + b) * CC + h * DD + db * 16 + l16] =
                f2b(OA[db][r] * invA);
            ctx[((size_t)tB * BB + b) * CC + h * DD + db * 16 + l16] =
                f2b(OB[db][r] * invB);
        }
    }
}

// ---------------------------------------------------------------------------
extern "C" void kernel_launch(void* const* d_in, const int* in_sizes, int n_in,
                              void* d_out, int out_size, void* d_ws, size_t ws_size,
                              hipStream_t stream) {
    const float* x  = (const float*)d_in[0];
    const float* Wq = (const float*)d_in[1];
    const float* Wk = (const float*)d_in[2];
    const float* Wv = (const float*)d_in[3];
    const float* Wo = (const float*)d_in[4];
    float* out = (float*)d_out;

    // Workspace (bf16): xb 8MB | Wb 4x2MB | Qb 8 | Kb 8 | Vb 8 | Vt 8 | Ctxb 8
    ushort* xb  = (ushort*)d_ws;
    ushort* Wb  = xb + (size_t)MM * CC;
    ushort* Wqb = Wb;
    ushort* Wkb = Wb + (size_t)CC * CC;
    ushort* Wvb = Wb + 2 * (size_t)CC * CC;
    ushort* Wob = Wb + 3 * (size_t)CC * CC;
    ushort* Qb  = Wb + 4 * (size_t)CC * CC;
    ushort* Kb  = Qb + (size_t)MM * CC;
    ushort* Vb  = Kb + (size_t)MM * CC;
    ushort* Vt  = Vb + (size_t)MM * CC;
    ushort* Ctxb = Vt + (size_t)MM * CC;

    conv_x<<<dim3(MM * CC / 4 / 256), 256, 0, stream>>>(x, xb);
    conv_w<<<dim3(CC * CC / 4 / 256, 4), 256, 0, stream>>>(Wq, Wk, Wv, Wo, Wb);

    gemm_mfma<1><<<dim3(MM / 128, 24), 256, 0, stream>>>(
        xb, Wqb, Wkb, Wvb, Qb, Kb, Vb, nullptr);

    vtrans<<<dim3(TT / 64, BB * HH), 256, 0, stream>>>(Vb, Vt);

    attn_mfma<<<dim3(TT / 128, BB * HH), 256, 0, stream>>>(Qb, Kb, Vt, Ctxb);

    gemm_mfma<0><<<dim3(MM / 128, CC / 128), 256, 0, stream>>>(
        Ctxb, Wob, nullptr, nullptr, nullptr, nullptr, nullptr, out);
}

// Round 6
// 182.175 us; speedup vs baseline: 21.6231x; 1.0270x over previous
//
#include <hip/hip_runtime.h>
#include <hip/hip_bf16.h>

// Problem constants (reference: T=2048, B=2, D_MODEL=1024, H=16, HEAD_DIM=64)
#define TT 2048
#define BB 2
#define CC 1024
#define HH 16
#define DD 64
#define MM (TT * BB)   // 4096 rows in the projection GEMMs

typedef short bf16x8 __attribute__((ext_vector_type(8)));   // 8 bf16 in 4 VGPRs
typedef float f32x4  __attribute__((ext_vector_type(4)));

// float -> bf16 (round-nearest-even), bit-level
__device__ inline ushort f2b(float f) {
    union { float f; unsigned u; } v; v.f = f;
    unsigned r = v.u + 0x7FFFu + ((v.u >> 16) & 1u);
    return (ushort)(r >> 16);
}

// pack 2 floats -> 2 bf16 in one dword
__device__ inline unsigned pack_bf16(float a, float b) {
    __hip_bfloat162 h = __float22bfloat162_rn(make_float2(a, b));
    union { __hip_bfloat162 h; unsigned u; } c; c.h = h;
    return c.u;
}

// async global->LDS, 16B per lane (GEMM staging only)
__device__ inline void gload_lds16(const ushort* g, ushort* l) {
    __builtin_amdgcn_global_load_lds(
        (const __attribute__((address_space(1))) void*)g,
        (__attribute__((address_space(3))) void*)l, 16, 0, 0);
}

// ---------------------------------------------------------------------------
// fp32 -> bf16 convert, x and all four W in one launch.
// ws layout: xb (MM*CC) | Wq|Wk|Wv|Wo (CC*CC each), contiguous bf16.
// ---------------------------------------------------------------------------
#define XQUADS (MM * CC / 4)          // 1048576
#define WQUADS (CC * CC / 4)          // 262144
__global__ __launch_bounds__(256) void conv_all(const float* __restrict__ x,
                                                const float* __restrict__ Wq,
                                                const float* __restrict__ Wk,
                                                const float* __restrict__ Wv,
                                                const float* __restrict__ Wo,
                                                ushort* __restrict__ dst) {
    int idx = blockIdx.x * 256 + threadIdx.x;    // quad index
    const float* src;
    int off;
    if (idx < XQUADS) {
        src = x; off = idx;
    } else {
        int wi = (idx - XQUADS) >> 18;           // WQUADS == 2^18
        off = (idx - XQUADS) & (WQUADS - 1);
        src = (wi == 0) ? Wq : (wi == 1) ? Wk : (wi == 2) ? Wv : Wo;
    }
    float4 v = ((const float4*)src)[off];
    ushort4 o = {f2b(v.x), f2b(v.y), f2b(v.z), f2b(v.w)};
    ((ushort4*)dst)[idx] = o;
}

// ---------------------------------------------------------------------------
// bf16 MFMA NT GEMM (m97 structure), 128x128 tile, BK=32, 4 waves (2x2).
// Fused QKV (grid.y = 24): wsel = by>>3 picks B/out; epilogue scatters bf16
// to (B,H,T,D); Q scaled by 1/sqrt(64)*log2(e) so attention uses exp2 raw.
// ---------------------------------------------------------------------------
__global__ __launch_bounds__(256) void gemm_qkv(const ushort* __restrict__ A,
                                                const ushort* __restrict__ B0,
                                                const ushort* __restrict__ B1,
                                                const ushort* __restrict__ B2,
                                                ushort* __restrict__ Oq,
                                                ushort* __restrict__ Ok,
                                                ushort* __restrict__ Ov) {
    __shared__ __align__(16) ushort As[128 * 32];
    __shared__ __align__(16) ushort Bs[128 * 32];

    const int tid = threadIdx.x;
    const int wave = tid >> 6, lane = tid & 63;
    const int quad = lane >> 4, l16 = lane & 15;
    const int wm = wave >> 1, wn = wave & 1;

    const int bm = blockIdx.x * 128;
    const int by = blockIdx.y;
    const int wsel = by >> 3;
    const ushort* Bp = (wsel == 0) ? B0 : (wsel == 1) ? B1 : B2;
    const int bn = (by & 7) * 128;

    const int srow = lane >> 2;
    const int scol = (lane & 3) * 8;

    f32x4 acc[4][4];
#pragma unroll
    for (int i = 0; i < 4; i++)
#pragma unroll
        for (int j = 0; j < 4; j++) acc[i][j] = (f32x4){0.f, 0.f, 0.f, 0.f};

    for (int k0 = 0; k0 < CC; k0 += 32) {
#pragma unroll
        for (int i = 0; i < 2; i++) {
            const int rbase = wave * 32 + i * 16;
            gload_lds16(A + (size_t)(bm + rbase + srow) * CC + k0 + scol,
                        As + rbase * 32);
            gload_lds16(Bp + (size_t)(bn + rbase + srow) * CC + k0 + scol,
                        Bs + rbase * 32);
        }
        __syncthreads();

        bf16x8 af[4], bf[4];
#pragma unroll
        for (int mi = 0; mi < 4; mi++)
            af[mi] = *(const bf16x8*)(As + (wm * 64 + mi * 16 + l16) * 32 + quad * 8);
#pragma unroll
        for (int ni = 0; ni < 4; ni++)
            bf[ni] = *(const bf16x8*)(Bs + (wn * 64 + ni * 16 + l16) * 32 + quad * 8);
#pragma unroll
        for (int mi = 0; mi < 4; mi++)
#pragma unroll
            for (int ni = 0; ni < 4; ni++)
                acc[mi][ni] = __builtin_amdgcn_mfma_f32_16x16x32_bf16(
                    af[mi], bf[ni], acc[mi][ni], 0, 0, 0);
        __syncthreads();
    }

#pragma unroll
    for (int mi = 0; mi < 4; mi++) {
#pragma unroll
        for (int r = 0; r < 4; r++) {
            const int m = bm + wm * 64 + mi * 16 + quad * 4 + r;
#pragma unroll
            for (int ni = 0; ni < 4; ni++) {
                const int colg = bn + wn * 64 + ni * 16 + l16;
                float v = acc[mi][ni][r];
                if (wsel == 0) v *= 0.18033688f;  // 1/sqrt(64) * log2(e)
                const int t = m >> 1, b = m & 1;
                const int h = colg >> 6, d = colg & 63;
                ushort* dst = (wsel == 0) ? Oq : (wsel == 1) ? Ok : Ov;
                dst[(((size_t)(b * HH + h)) * TT + t) * DD + d] = f2b(v);
            }
        }
    }
}

// ---------------------------------------------------------------------------
// Out-projection GEMM: 128x64 tile (512 blocks = 2/CU), BK=32, fp32 output.
// Wave w owns rows [w*32, w*32+32) x 64 cols: 2x4 MFMAs of 16x16x32.
// ---------------------------------------------------------------------------
__global__ __launch_bounds__(256) void gemm_out(const ushort* __restrict__ A,
                                                const ushort* __restrict__ Bm,
                                                float* __restrict__ Of) {
    __shared__ __align__(16) ushort As[128 * 32];   // 8 KB
    __shared__ __align__(16) ushort Bs[64 * 32];    // 4 KB

    const int tid = threadIdx.x;
    const int wave = tid >> 6, lane = tid & 63;
    const int quad = lane >> 4, l16 = lane & 15;

    const int bm = blockIdx.x * 128;
    const int bn = blockIdx.y * 64;

    const int srow = lane >> 2;
    const int scol = (lane & 3) * 8;

    f32x4 acc[2][4];
#pragma unroll
    for (int i = 0; i < 2; i++)
#pragma unroll
        for (int j = 0; j < 4; j++) acc[i][j] = (f32x4){0.f, 0.f, 0.f, 0.f};

    for (int k0 = 0; k0 < CC; k0 += 32) {
#pragma unroll
        for (int i = 0; i < 2; i++) {
            const int rbase = wave * 32 + i * 16;
            gload_lds16(A + (size_t)(bm + rbase + srow) * CC + k0 + scol,
                        As + rbase * 32);
        }
        gload_lds16(Bm + (size_t)(bn + wave * 16 + srow) * CC + k0 + scol,
                    Bs + wave * 16 * 32);
        __syncthreads();

        bf16x8 af[2], bf[4];
#pragma unroll
        for (int mi = 0; mi < 2; mi++)
            af[mi] = *(const bf16x8*)(As + (wave * 32 + mi * 16 + l16) * 32 + quad * 8);
#pragma unroll
        for (int ni = 0; ni < 4; ni++)
            bf[ni] = *(const bf16x8*)(Bs + (ni * 16 + l16) * 32 + quad * 8);
#pragma unroll
        for (int mi = 0; mi < 2; mi++)
#pragma unroll
            for (int ni = 0; ni < 4; ni++)
                acc[mi][ni] = __builtin_amdgcn_mfma_f32_16x16x32_bf16(
                    af[mi], bf[ni], acc[mi][ni], 0, 0, 0);
        __syncthreads();
    }

#pragma unroll
    for (int mi = 0; mi < 2; mi++)
#pragma unroll
        for (int r = 0; r < 4; r++) {
            const int m = bm + wave * 32 + mi * 16 + quad * 4 + r;
#pragma unroll
            for (int ni = 0; ni < 4; ni++)
                Of[(size_t)m * CC + bn + ni * 16 + l16] = acc[mi][ni][r];
        }
}

// ---------------------------------------------------------------------------
// V transpose with baked column permutation: output column j' holds key
// j = (j'&3)*16 + (j'>>2) within each 64-key tile (matches packed P writes).
// ---------------------------------------------------------------------------
__global__ __launch_bounds__(256) void vtrans(const ushort* __restrict__ Vb,
                                              ushort* __restrict__ Vt) {
    __shared__ __align__(16) ushort Ls[64 * 80];
    const int bh = blockIdx.y;
    const int t0 = blockIdx.x * 64;
    const int e = threadIdx.x;
    const size_t bsrc = (size_t)bh * TT * DD;
    const size_t bdst = (size_t)bh * DD * TT;

#pragma unroll
    for (int p = 0; p < 2; p++) {
        int r = p * 32 + (e >> 3);
        int oct = e & 7;
        *(uint4*)(Ls + r * 80 + oct * 8) =
            *(const uint4*)(Vb + bsrc + (size_t)(t0 + r) * DD + oct * 8);
    }
    __syncthreads();
#pragma unroll
    for (int p = 0; p < 2; p++) {
        int d = p * 32 + (e >> 3);
        int toct = e & 7;
        ushort tmp[8];
#pragma unroll
        for (int u = 0; u < 8; u++) {
            int jp = toct * 8 + u;
            int js = (jp & 3) * 16 + (jp >> 2);
            tmp[u] = Ls[js * 80 + d];
        }
        *(uint4*)(Vt + bdst + (size_t)d * TT + t0 + toct * 8) = *(uint4*)tmp;
    }
}

// ---------------------------------------------------------------------------
// Fused dual-q-set flash step for one 64-key tile. AM: 0=A full, 1=A diag,
// 2=A skip. BD: B diag. Separate P buffers let A/B chains interleave; shared
// K/V fragments are loaded once and feed back-to-back independent MFMAs.
// Max-free softmax: p = exp2(min(s,60)), l per-lane (reduced in epilogue).
// ---------------------------------------------------------------------------
template <int AM, bool BD>
__device__ __forceinline__ void attn_step2(const bf16x8* qaA, const bf16x8* qaB,
                                           f32x4* OA, f32x4* OB,
                                           float* lA, float* lB,
                                           const ushort* Ks, const ushort* Vs,
                                           ushort* PA, ushort* PB,
                                           int j0, int q0A, int q0B,
                                           int quad, int l16) {
    f32x4 SA[4], SB[4];
#pragma unroll
    for (int nb = 0; nb < 4; nb++) {
        SB[nb] = (f32x4){0.f, 0.f, 0.f, 0.f};
        if (AM < 2) SA[nb] = (f32x4){0.f, 0.f, 0.f, 0.f};
    }
#pragma unroll
    for (int c = 0; c < 2; c++)
#pragma unroll
        for (int nb = 0; nb < 4; nb++) {
            bf16x8 k = *(const bf16x8*)(Ks + (nb * 16 + l16) * 72 + c * 32 + quad * 8);
            SB[nb] = __builtin_amdgcn_mfma_f32_16x16x32_bf16(qaB[c], k, SB[nb], 0, 0, 0);
            if (AM < 2)
                SA[nb] = __builtin_amdgcn_mfma_f32_16x16x32_bf16(qaA[c], k, SA[nb], 0, 0, 0);
        }

#pragma unroll
    for (int r = 0; r < 4; r++) {
        // B set
        {
            const int qg = q0B + quad * 4 + r;
            float p[4];
#pragma unroll
            for (int nb = 0; nb < 4; nb++) {
                float s = SB[nb][r];
                if (BD) { if (j0 + nb * 16 + l16 > qg) s = -1e30f; }
                p[nb] = __builtin_amdgcn_exp2f(fminf(s, 60.f));
            }
            lB[r] += (p[0] + p[1]) + (p[2] + p[3]);
            uint2 w; w.x = pack_bf16(p[0], p[1]); w.y = pack_bf16(p[2], p[3]);
            *(uint2*)(PB + (quad * 4 + r) * 72 + l16 * 4) = w;
        }
        // A set
        if (AM < 2) {
            const int qg = q0A + quad * 4 + r;
            float p[4];
#pragma unroll
            for (int nb = 0; nb < 4; nb++) {
                float s = SA[nb][r];
                if (AM == 1) { if (j0 + nb * 16 + l16 > qg) s = -1e30f; }
                p[nb] = __builtin_amdgcn_exp2f(fminf(s, 60.f));
            }
            lA[r] += (p[0] + p[1]) + (p[2] + p[3]);
            uint2 w; w.x = pack_bf16(p[0], p[1]); w.y = pack_bf16(p[2], p[3]);
            *(uint2*)(PA + (quad * 4 + r) * 72 + l16 * 4) = w;
        }
    }

#pragma unroll
    for (int c = 0; c < 2; c++) {
        bf16x8 paB = *(const bf16x8*)(PB + l16 * 72 + c * 32 + quad * 8);
        bf16x8 paA;
        if (AM < 2) paA = *(const bf16x8*)(PA + l16 * 72 + c * 32 + quad * 8);
#pragma unroll
        for (int db = 0; db < 4; db++) {
            bf16x8 v = *(const bf16x8*)(Vs + (db * 16 + l16) * 72 + c * 32 + quad * 8);
            OB[db] = __builtin_amdgcn_mfma_f32_16x16x32_bf16(paB, v, OB[db], 0, 0, 0);
            if (AM < 2)
                OA[db] = __builtin_amdgcn_mfma_f32_16x16x32_bf16(paA, v, OA[db], 0, 0, 0);
        }
    }
}

// ---------------------------------------------------------------------------
// Paired-tile flash MFMA attention: block p handles q-tiles p and 31-p
// (uniform 33 tile-visits). K/V staged once per tile; register prefetch of
// tile kt+1 overlaps compute; dual P buffers give two independent chains.
// ---------------------------------------------------------------------------
__global__ __launch_bounds__(256, 2) void attn_mfma(const ushort* __restrict__ Qb,
                                                    const ushort* __restrict__ Kb,
                                                    const ushort* __restrict__ Vt,
                                                    ushort* __restrict__ ctx) {
    __shared__ __align__(16) ushort Ks[64 * 72];        // [j][k]
    __shared__ __align__(16) ushort Vs[64 * 72];        // [d][j']
    __shared__ __align__(16) ushort PsA[4 * 16 * 72];   // per-wave P_A[m][j']
    __shared__ __align__(16) ushort PsB[4 * 16 * 72];   // per-wave P_B[m][j']

    const int tid  = threadIdx.x;
    const int wave = tid >> 6;
    const int lane = tid & 63;
    const int quad = lane >> 4;
    const int l16  = lane & 15;

    const int p  = blockIdx.x;                    // 0..15
    const int bh = blockIdx.y;
    const int qtA = p, qtB = (TT / 64 - 1) - p;   // qtA < 16 <= qtB
    const int q0A = qtA * 64 + wave * 16;
    const int q0B = qtB * 64 + wave * 16;

    const size_t baseQK = (size_t)bh * TT * DD;
    const size_t baseVt = (size_t)bh * DD * TT;

    bf16x8 qaA[2], qaB[2];
    {
        const ushort* qp = Qb + baseQK + (size_t)(q0A + l16) * DD + quad * 8;
        qaA[0] = *(const bf16x8*)(qp);
        qaA[1] = *(const bf16x8*)(qp + 32);
        const ushort* qp2 = Qb + baseQK + (size_t)(q0B + l16) * DD + quad * 8;
        qaB[0] = *(const bf16x8*)(qp2);
        qaB[1] = *(const bf16x8*)(qp2 + 32);
    }

    f32x4 OA[4], OB[4];
#pragma unroll
    for (int i = 0; i < 4; i++) {
        OA[i] = (f32x4){0.f, 0.f, 0.f, 0.f};
        OB[i] = (f32x4){0.f, 0.f, 0.f, 0.f};
    }
    float lA[4] = {0.f, 0.f, 0.f, 0.f};
    float lB[4] = {0.f, 0.f, 0.f, 0.f};

    ushort* PA = PsA + wave * 16 * 72;
    ushort* PB = PsB + wave * 16 * 72;

    const int row0 = tid >> 3;
    const int oct  = tid & 7;

    uint4 kr0, kr1, vr0, vr1;
    kr0 = *(const uint4*)(Kb + baseQK + (size_t)row0 * DD + oct * 8);
    kr1 = *(const uint4*)(Kb + baseQK + (size_t)(row0 + 32) * DD + oct * 8);
    vr0 = *(const uint4*)(Vt + baseVt + (size_t)row0 * TT + oct * 8);
    vr1 = *(const uint4*)(Vt + baseVt + (size_t)(row0 + 32) * TT + oct * 8);

    for (int kt = 0; kt <= qtB; kt++) {
        const int j0 = kt * 64;

        *(uint4*)(Ks + row0 * 72 + oct * 8) = kr0;
        *(uint4*)(Ks + (row0 + 32) * 72 + oct * 8) = kr1;
        *(uint4*)(Vs + row0 * 72 + oct * 8) = vr0;
        *(uint4*)(Vs + (row0 + 32) * 72 + oct * 8) = vr1;
        __syncthreads();

        if (kt < qtB) {
            const int jn = j0 + 64;
            kr0 = *(const uint4*)(Kb + baseQK + (size_t)(jn + row0) * DD + oct * 8);
            kr1 = *(const uint4*)(Kb + baseQK + (size_t)(jn + row0 + 32) * DD + oct * 8);
            vr0 = *(const uint4*)(Vt + baseVt + (size_t)row0 * TT + jn + oct * 8);
            vr1 = *(const uint4*)(Vt + baseVt + (size_t)(row0 + 32) * TT + jn + oct * 8);
        }

        if (kt < qtA)
            attn_step2<0, false>(qaA, qaB, OA, OB, lA, lB, Ks, Vs, PA, PB,
                                 j0, q0A, q0B, quad, l16);
        else if (kt == qtA)
            attn_step2<1, false>(qaA, qaB, OA, OB, lA, lB, Ks, Vs, PA, PB,
                                 j0, q0A, q0B, quad, l16);
        else if (kt < qtB)
            attn_step2<2, false>(qaA, qaB, OA, OB, lA, lB, Ks, Vs, PA, PB,
                                 j0, q0A, q0B, quad, l16);
        else
            attn_step2<2, true>(qaA, qaB, OA, OB, lA, lB, Ks, Vs, PA, PB,
                                j0, q0A, q0B, quad, l16);
        __syncthreads();
    }

    // epilogue: row-reduce l across 16-lane groups, normalize, store bf16
    const int b = bh >> 4, h = bh & 15;
#pragma unroll
    for (int r = 0; r < 4; r++) {
        float la = lA[r], lb = lB[r];
        la += __shfl_xor(la, 1); la += __shfl_xor(la, 2);
        la += __shfl_xor(la, 4); la += __shfl_xor(la, 8);
        lb += __shfl_xor(lb, 1); lb += __shfl_xor(lb, 2);
        lb += __shfl_xor(lb, 4); lb += __shfl_xor(lb, 8);
        const float invA = 1.f / la;
        const float invB = 1.f / lb;
        const int tA = q0A + quad * 4 + r;
        const int tB = q0B + quad * 4 + r;
#pragma unroll
        for (int db = 0; db < 4; db++) {
            ctx[((size_t)tA * BB + b) * CC + h * DD + db * 16 + l16] =
                f2b(OA[db][r] * invA);
            ctx[((size_t)tB * BB + b) * CC + h * DD + db * 16 + l16] =
                f2b(OB[db][r] * invB);
        }
    }
}

// ---------------------------------------------------------------------------
extern "C" void kernel_launch(void* const* d_in, const int* in_sizes, int n_in,
                              void* d_out, int out_size, void* d_ws, size_t ws_size,
                              hipStream_t stream) {
    const float* x  = (const float*)d_in[0];
    const float* Wq = (const float*)d_in[1];
    const float* Wk = (const float*)d_in[2];
    const float* Wv = (const float*)d_in[3];
    const float* Wo = (const float*)d_in[4];
    float* out = (float*)d_out;

    // Workspace (bf16): xb 8MB | Wb 4x2MB | Qb 8 | Kb 8 | Vb 8 | Vt 8 | Ctxb 8
    ushort* xb  = (ushort*)d_ws;
    ushort* Wb  = xb + (size_t)MM * CC;
    ushort* Wqb = Wb;
    ushort* Wkb = Wb + (size_t)CC * CC;
    ushort* Wvb = Wb + 2 * (size_t)CC * CC;
    ushort* Wob = Wb + 3 * (size_t)CC * CC;
    ushort* Qb  = Wb + 4 * (size_t)CC * CC;
    ushort* Kb  = Qb + (size_t)MM * CC;
    ushort* Vb  = Kb + (size_t)MM * CC;
    ushort* Vt  = Vb + (size_t)MM * CC;
    ushort* Ctxb = Vt + (size_t)MM * CC;

    conv_all<<<dim3((XQUADS + 4 * WQUADS) / 256), 256, 0, stream>>>(
        x, Wq, Wk, Wv, Wo, xb);

    gemm_qkv<<<dim3(MM / 128, 24), 256, 0, stream>>>(
        xb, Wqb, Wkb, Wvb, Qb, Kb, Vb);

    vtrans<<<dim3(TT / 64, BB * HH), 256, 0, stream>>>(Vb, Vt);

    attn_mfma<<<dim3(TT / 128, BB * HH), 256, 0, stream>>>(Qb, Kb, Vt, Ctxb);

    gemm_out<<<dim3(MM / 128, CC / 64), 256, 0, stream>>>(Ctxb, Wob, out);
}